// Round 13
// baseline (47.005 us; speedup 1.0000x reference)
//
#include <hip/hip_runtime.h>
#include <math.h>

// Sizes (fixed by the problem)
#define Bb 8
#define Tt 32
#define Hh 64
#define Ww 64
#define Cc 3
#define Ff 24
#define Uu 128

// ---------------------------------------------------------------------------
// Kernel 1: fused per-frame stats + analytic double-conv + global-avg-pool
// + input-part of gate preactivations. G layout GATE-TRANSPOSED:
// G[(t*8+b)*512 + u*4 + g]. Unchanged from round 12.
// ---------------------------------------------------------------------------
__global__ void convfeat_kernel(const float* __restrict__ x,
                                const float* __restrict__ w1, const float* __restrict__ b1,
                                const float* __restrict__ w2, const float* __restrict__ b2,
                                const float* __restrict__ Wf, const float* __restrict__ bf,
                                const float* __restrict__ Wi, const float* __restrict__ bi,
                                const float* __restrict__ Wc, const float* __restrict__ bc,
                                const float* __restrict__ Wo, const float* __restrict__ bo,
                                float* __restrict__ G) {
    int n = blockIdx.x;                       // frame = b*T + t
    const float* xf = x + (size_t)n * (Hh * Ww * Cc);
    int tid  = threadIdx.x;                   // 0..255
    int row  = tid >> 2;
    int part = tid & 3;

    __shared__ float partial[256][3];
    __shared__ float rowsum[64][3];
    __shared__ float colv[64][12];
    __shared__ float st[75];                  // [c*25 + j]
    __shared__ float yst[24][9];
    __shared__ float feats[24];

    float s0 = 0.f, s1 = 0.f, s2 = 0.f;
    const float4* p4 = (const float4*)(xf + (row * Ww + part * 16) * Cc);
#pragma unroll
    for (int i = 0; i < 12; ++i) {
        float4 v = p4[i];
        int j = i * 4;
        float vv[4] = {v.x, v.y, v.z, v.w};
#pragma unroll
        for (int l = 0; l < 4; ++l) {
            int c = (j + l) % 3;
            if (c == 0) s0 += vv[l]; else if (c == 1) s1 += vv[l]; else s2 += vv[l];
        }
    }
    partial[tid][0] = s0; partial[tid][1] = s1; partial[tid][2] = s2;

    if (tid < 64) {
        int r = tid;
#pragma unroll
        for (int w4 = 0; w4 < 4; ++w4) {
            int w = (w4 < 2) ? w4 : 60 + w4;
#pragma unroll
            for (int c = 0; c < 3; ++c) colv[r][w4 * 3 + c] = xf[(r * Ww + w) * Cc + c];
        }
    }
    __syncthreads();

    if (part == 0) {
#pragma unroll
        for (int c = 0; c < 3; ++c)
            rowsum[row][c] = partial[tid][c] + partial[tid + 1][c]
                           + partial[tid + 2][c] + partial[tid + 3][c];
    }
    __syncthreads();

    if (tid < 3) {
        float t = 0.f;
        for (int r = 0; r < 64; ++r) t += rowsum[r][tid];
        st[tid * 25 + 0] = t;
    }
    if (tid >= 4 && tid < 16) {
        int k = tid - 4; int ri = k / 3, c = k % 3;
        int r = (ri < 2) ? ri : 60 + ri;
        st[c * 25 + 1 + ri] = rowsum[r][c];
    }
    if (tid >= 64 && tid < 76) {
        int k = tid - 64;
        float t = 0.f;
        for (int r = 0; r < 64; ++r) t += colv[r][k];
        int wi = k / 3, c = k % 3;
        st[c * 25 + 5 + wi] = t;
    }
    if (tid >= 128 && tid < 176) {
        int k = tid - 128; int pos = k / 3, c = k % 3;
        int ri = pos >> 2, wi = pos & 3;
        int r = (ri < 2) ? ri : 60 + ri;
        int w = (wi < 2) ? wi : 60 + wi;
        st[c * 25 + 9 + pos] = xf[(r * Ww + w) * Cc + c];
    }
    __syncthreads();

    if (tid < 24) {
        int f = tid;
        float Sy = 0, r0 = 0, r63 = 0, c0 = 0, c63 = 0, y00 = 0, y0W = 0, yH0 = 0, yHW = 0;
        for (int c = 0; c < 3; ++c) {
            const float* S = st + c * 25;
            float Sx = S[0];
            float rX[4] = {S[1], S[2], S[3], S[4]};
            float cX[4] = {S[5], S[6], S[7], S[8]};
            const float* X = S + 9;
            #define W1(p, q) w1[(((p) * 3 + (q)) * 3 + c) * 24 + f]
#pragma unroll
            for (int p = 0; p < 3; ++p)
#pragma unroll
                for (int q = 0; q < 3; ++q) {
                    float t = Sx;
                    if (p == 0) t -= rX[3];
                    if (p == 2) t -= rX[0];
                    if (q == 0) t -= cX[3];
                    if (q == 2) t -= cX[0];
                    if (p == 0 && q == 0) t += X[3 * 4 + 3];
                    if (p == 0 && q == 2) t += X[3 * 4 + 0];
                    if (p == 2 && q == 0) t += X[0 * 4 + 3];
                    if (p == 2 && q == 2) t += X[0 * 4 + 0];
                    Sy += W1(p, q) * t;
                }
#pragma unroll
            for (int q = 0; q < 3; ++q) {
                float Rr0  = rX[0] - ((q == 0) ? X[0 * 4 + 3] : 0.f) - ((q == 2) ? X[0 * 4 + 0] : 0.f);
                float Rr1  = rX[1] - ((q == 0) ? X[1 * 4 + 3] : 0.f) - ((q == 2) ? X[1 * 4 + 0] : 0.f);
                float Rr62 = rX[2] - ((q == 0) ? X[2 * 4 + 3] : 0.f) - ((q == 2) ? X[2 * 4 + 0] : 0.f);
                float Rr63 = rX[3] - ((q == 0) ? X[3 * 4 + 3] : 0.f) - ((q == 2) ? X[3 * 4 + 0] : 0.f);
                r0  += W1(1, q) * Rr0  + W1(2, q) * Rr1;
                r63 += W1(0, q) * Rr62 + W1(1, q) * Rr63;
            }
#pragma unroll
            for (int p = 0; p < 3; ++p) {
                float Rc0  = cX[0] - ((p == 0) ? X[3 * 4 + 0] : 0.f) - ((p == 2) ? X[0 * 4 + 0] : 0.f);
                float Rc1  = cX[1] - ((p == 0) ? X[3 * 4 + 1] : 0.f) - ((p == 2) ? X[0 * 4 + 1] : 0.f);
                float Rc62 = cX[2] - ((p == 0) ? X[3 * 4 + 2] : 0.f) - ((p == 2) ? X[0 * 4 + 2] : 0.f);
                float Rc63 = cX[3] - ((p == 0) ? X[3 * 4 + 3] : 0.f) - ((p == 2) ? X[0 * 4 + 3] : 0.f);
                c0  += W1(p, 1) * Rc0  + W1(p, 2) * Rc1;
                c63 += W1(p, 0) * Rc62 + W1(p, 1) * Rc63;
            }
            y00 += W1(1, 1) * X[0 * 4 + 0] + W1(1, 2) * X[0 * 4 + 1]
                 + W1(2, 1) * X[1 * 4 + 0] + W1(2, 2) * X[1 * 4 + 1];
            y0W += W1(1, 0) * X[0 * 4 + 2] + W1(1, 1) * X[0 * 4 + 3]
                 + W1(2, 0) * X[1 * 4 + 2] + W1(2, 1) * X[1 * 4 + 3];
            yH0 += W1(0, 1) * X[2 * 4 + 0] + W1(0, 2) * X[2 * 4 + 1]
                 + W1(1, 1) * X[3 * 4 + 0] + W1(1, 2) * X[3 * 4 + 1];
            yHW += W1(0, 0) * X[2 * 4 + 2] + W1(0, 1) * X[2 * 4 + 3]
                 + W1(1, 0) * X[3 * 4 + 2] + W1(1, 1) * X[3 * 4 + 3];
            #undef W1
        }
        float bb = b1[f];
        yst[f][0] = Sy + 4096.f * bb;
        yst[f][1] = r0 + 64.f * bb;
        yst[f][2] = r63 + 64.f * bb;
        yst[f][3] = c0 + 64.f * bb;
        yst[f][4] = c63 + 64.f * bb;
        yst[f][5] = y00 + bb; yst[f][6] = y0W + bb;
        yst[f][7] = yH0 + bb; yst[f][8] = yHW + bb;
    }
    __syncthreads();

    if (tid < 24) {
        int g = tid;
        float acc = 0.f;
        for (int f = 0; f < 24; ++f) {
            float Sy = yst[f][0], rY0 = yst[f][1], rY63 = yst[f][2], cY0 = yst[f][3], cY63 = yst[f][4];
            float yc00 = yst[f][5], yc0W = yst[f][6], ycH0 = yst[f][7], ycHW = yst[f][8];
#pragma unroll
            for (int p = 0; p < 3; ++p)
#pragma unroll
                for (int q = 0; q < 3; ++q) {
                    float t = Sy;
                    if (p == 0) t -= rY63;
                    if (p == 2) t -= rY0;
                    if (q == 0) t -= cY63;
                    if (q == 2) t -= cY0;
                    if (p == 0 && q == 0) t += ycHW;
                    if (p == 0 && q == 2) t += ycH0;
                    if (p == 2 && q == 0) t += yc0W;
                    if (p == 2 && q == 2) t += yc00;
                    acc += w2[(((p * 3 + q) * 24 + f) * 24) + g] * t;
                }
        }
        feats[g] = b2[g] + acc * (1.f / 4096.f);
    }
    __syncthreads();

    int b = n >> 5, t = n & 31;               // Tt = 32
    float* Gdst = G + ((size_t)(t * Bb + b)) * 512;
#pragma unroll
    for (int rep = 0; rep < 2; ++rep) {
        int col = tid + rep * 256;
        int gg = col >> 7, u = col & 127;
        const float* W    = (gg == 0) ? Wf : (gg == 1) ? Wi : (gg == 2) ? Wc : Wo;
        const float* bias = (gg == 0) ? bf : (gg == 1) ? bi : (gg == 2) ? bc : bo;
        float acc = bias[u];
#pragma unroll
        for (int k = 0; k < Ff; ++k) acc += feats[k] * W[k * Uu + u];
        Gdst[u * 4 + gg] = acc;               // [u][gate] layout
    }
}

// ===========================================================================
// Kernel 2: LSTM — HAND-ALLOCATED INLINE ASM (see round-13 theory).
// ===========================================================================
#define LD8(d0,d1,d2,d3,d4,d5,d6,d7) \
  "global_load_dword v" #d0 ", v[46:47], off\n\t" \
  "global_load_dword v" #d1 ", v[46:47], off offset:512\n\t" \
  "global_load_dword v" #d2 ", v[46:47], off offset:1024\n\t" \
  "global_load_dword v" #d3 ", v[46:47], off offset:1536\n\t" \
  "global_load_dword v" #d4 ", v[46:47], off offset:2048\n\t" \
  "global_load_dword v" #d5 ", v[46:47], off offset:2560\n\t" \
  "global_load_dword v" #d6 ", v[46:47], off offset:3072\n\t" \
  "global_load_dword v" #d7 ", v[46:47], off offset:3584\n\t"
#define BUMP \
  "v_add_co_u32 v46, vcc, 0x1000, v46\n\t" \
  "v_addc_co_u32 v47, vcc, 0, v47, vcc\n\t"
#define PA2(rA,fA,iA,cA,oA, rB,fB,iB,cB,oB) \
  "v_readlane_b32 s20, v32, " #rA "\n\t" \
  "v_readlane_b32 s21, v32, " #rB "\n\t" \
  "v_fmac_f32 v34, s20, v" #fA "\n\t" \
  "v_fmac_f32 v35, s20, v" #iA "\n\t" \
  "v_fmac_f32 v36, s20, v" #cA "\n\t" \
  "v_fmac_f32 v37, s20, v" #oA "\n\t" \
  "v_fmac_f32 v34, s21, v" #fB "\n\t" \
  "v_fmac_f32 v35, s21, v" #iB "\n\t" \
  "v_fmac_f32 v36, s21, v" #cB "\n\t" \
  "v_fmac_f32 v37, s21, v" #oB "\n\t"

__global__ __launch_bounds__(512) void lstm_kernel(
        const float* __restrict__ G,
        const float* __restrict__ Wf, const float* __restrict__ Wi,
        const float* __restrict__ Wc, const float* __restrict__ Wo,
        const float* __restrict__ out_w, const float* __restrict__ out_b,
        float* __restrict__ out) {
    int b   = blockIdx.x;
    int tid = threadIdx.x;
    int w   = tid >> 6;                       // wave 0..7
    int l   = tid & 63;
    int q   = w >> 1;                         // row chunk (rows 32q..+32)
    int uc  = ((w & 1) << 6) | l;             // this thread's gate-column unit
    int u   = (q << 5) | (l & 31);            // phase-B unit

    __shared__ __align__(16) float Gl[Tt][Uu * 4];     // 64 KB, [t][u*4+g]
    __shared__ __align__(16) float prt[2][4][Uu][4];   // 16 KB
    __shared__ __align__(16) float hist[Tt][Uu];       // 16 KB

    // Prologue: copy G[b] slab (32x512) to LDS, coalesced.
    {
        int r  = tid >> 4;
        int cc = (tid & 15) * 32;
        const float4* src = (const float4*)(G + ((size_t)(r * Bb + b)) * 512 + cc);
        float4* dst = (float4*)(&Gl[r][cc]);
#pragma unroll
        for (int i = 0; i < 8; ++i) dst[i] = src[i];
    }
    __syncthreads();

    const float* Wfp = Wf + (size_t)(Ff + 32 * q) * Uu + uc;
    const float* Wip = Wi + (size_t)(Ff + 32 * q) * Uu + uc;
    const float* Wcp = Wc + (size_t)(Ff + 32 * q) * Uu + uc;
    const float* Wop = Wo + (size_t)(Ff + 32 * q) * Uu + uc;
    unsigned f_lo = (unsigned)(uintptr_t)Wfp, f_hi = (unsigned)((uintptr_t)Wfp >> 32);
    unsigned i_lo = (unsigned)(uintptr_t)Wip, i_hi = (unsigned)((uintptr_t)Wip >> 32);
    unsigned c_lo = (unsigned)(uintptr_t)Wcp, c_hi = (unsigned)((uintptr_t)Wcp >> 32);
    unsigned o_lo = (unsigned)(uintptr_t)Wop, o_hi = (unsigned)((uintptr_t)Wop >> 32);
    unsigned pw = (unsigned)(uintptr_t)&prt[0][q][uc][0];
    unsigned pr = (unsigned)(uintptr_t)&prt[0][0][u][0];
    unsigned ga = (unsigned)(uintptr_t)&Gl[0][u * 4];
    unsigned ha = (unsigned)(uintptr_t)&hist[0][u];

    asm volatile(
        // ---------- weight loads into fixed v64..v191 ----------
        "v_mov_b32 v46, %0\n\t" "v_mov_b32 v47, %1\n\t"
        LD8(64,65,66,67,68,69,70,71) BUMP
        LD8(72,73,74,75,76,77,78,79) BUMP
        LD8(80,81,82,83,84,85,86,87) BUMP
        LD8(88,89,90,91,92,93,94,95)
        "v_mov_b32 v46, %2\n\t" "v_mov_b32 v47, %3\n\t"
        LD8(96,97,98,99,100,101,102,103) BUMP
        LD8(104,105,106,107,108,109,110,111) BUMP
        LD8(112,113,114,115,116,117,118,119) BUMP
        LD8(120,121,122,123,124,125,126,127)
        "v_mov_b32 v46, %4\n\t" "v_mov_b32 v47, %5\n\t"
        LD8(128,129,130,131,132,133,134,135) BUMP
        LD8(136,137,138,139,140,141,142,143) BUMP
        LD8(144,145,146,147,148,149,150,151) BUMP
        LD8(152,153,154,155,156,157,158,159)
        "v_mov_b32 v46, %6\n\t" "v_mov_b32 v47, %7\n\t"
        LD8(160,161,162,163,164,165,166,167) BUMP
        LD8(168,169,170,171,172,173,174,175) BUMP
        LD8(176,177,178,179,180,181,182,183) BUMP
        LD8(184,185,186,187,188,189,190,191)
        "s_waitcnt vmcnt(0)\n\t"
        // ---------- loop state ----------
        "v_mov_b32 v40, %8\n\t"
        "v_mov_b32 v41, %9\n\t"
        "v_mov_b32 v42, %10\n\t"
        "v_mov_b32 v43, %11\n\t"
        "v_mov_b32 v32, 0\n\t"
        "v_mov_b32 v33, 0\n\t"
        "s_mov_b32 s22, 32\n\t"
        "Lstep_%=:\n\t"
        // ---------- phase A ----------
        "v_mov_b32 v34, 0\n\t" "v_mov_b32 v35, 0\n\t"
        "v_mov_b32 v36, 0\n\t" "v_mov_b32 v37, 0\n\t"
        PA2(0,64,96,128,160,   1,65,97,129,161)
        PA2(2,66,98,130,162,   3,67,99,131,163)
        PA2(4,68,100,132,164,  5,69,101,133,165)
        PA2(6,70,102,134,166,  7,71,103,135,167)
        PA2(8,72,104,136,168,  9,73,105,137,169)
        PA2(10,74,106,138,170, 11,75,107,139,171)
        PA2(12,76,108,140,172, 13,77,109,141,173)
        PA2(14,78,110,142,174, 15,79,111,143,175)
        PA2(16,80,112,144,176, 17,81,113,145,177)
        PA2(18,82,114,146,178, 19,83,115,147,179)
        PA2(20,84,116,148,180, 21,85,117,149,181)
        PA2(22,86,118,150,182, 23,87,119,151,183)
        PA2(24,88,120,152,184, 25,89,121,153,185)
        PA2(26,90,122,154,186, 27,91,123,155,187)
        PA2(28,92,124,156,188, 29,93,125,157,189)
        PA2(30,94,126,158,190, 31,95,127,159,191)
        "ds_write_b128 v40, v[34:37]\n\t"
        "s_waitcnt lgkmcnt(0)\n\t"
        "s_barrier\n\t"
        // ---------- phase B ----------
        "ds_read_b128 v[44:47], v41\n\t"
        "ds_read_b128 v[48:51], v41 offset:2048\n\t"
        "ds_read_b128 v[52:55], v41 offset:4096\n\t"
        "ds_read_b128 v[56:59], v41 offset:6144\n\t"
        "ds_read_b128 v[60:63], v42\n\t"
        "s_waitcnt lgkmcnt(0)\n\t"
        "v_add_f32 v44, v44, v48\n\t" "v_add_f32 v45, v45, v49\n\t"
        "v_add_f32 v46, v46, v50\n\t" "v_add_f32 v47, v47, v51\n\t"
        "v_add_f32 v52, v52, v56\n\t" "v_add_f32 v53, v53, v57\n\t"
        "v_add_f32 v54, v54, v58\n\t" "v_add_f32 v55, v55, v59\n\t"
        "v_add_f32 v44, v44, v52\n\t" "v_add_f32 v45, v45, v53\n\t"
        "v_add_f32 v46, v46, v54\n\t" "v_add_f32 v47, v47, v55\n\t"
        "v_add_f32 v44, v44, v60\n\t" "v_add_f32 v45, v45, v61\n\t"
        "v_add_f32 v46, v46, v62\n\t" "v_add_f32 v47, v47, v63\n\t"
        "v_mul_f32 v48, 0xbfb8aa3b, v44\n\t"
        "v_mul_f32 v49, 0xbfb8aa3b, v45\n\t"
        "v_mul_f32 v50, 0xc038aa3b, v46\n\t"
        "v_mul_f32 v51, 0xbfb8aa3b, v47\n\t"
        "v_exp_f32 v48, v48\n\t" "v_exp_f32 v49, v49\n\t"
        "v_exp_f32 v50, v50\n\t" "v_exp_f32 v51, v51\n\t"
        "s_nop 1\n\t"
        "v_add_f32 v48, 1.0, v48\n\t" "v_add_f32 v49, 1.0, v49\n\t"
        "v_add_f32 v50, 1.0, v50\n\t" "v_add_f32 v51, 1.0, v51\n\t"
        "v_rcp_f32 v48, v48\n\t" "v_rcp_f32 v49, v49\n\t"
        "v_rcp_f32 v50, v50\n\t" "v_rcp_f32 v51, v51\n\t"
        "s_nop 1\n\t"
        "v_mul_f32 v50, 2.0, v50\n\t"
        "v_add_f32 v50, -1.0, v50\n\t"
        "v_mul_f32 v33, v33, v48\n\t"
        "v_fmac_f32 v33, v49, v50\n\t"
        "v_mul_f32 v52, 0xc038aa3b, v33\n\t"
        "v_exp_f32 v52, v52\n\t"
        "s_nop 1\n\t"
        "v_add_f32 v52, 1.0, v52\n\t"
        "v_rcp_f32 v52, v52\n\t"
        "s_nop 1\n\t"
        "v_mul_f32 v52, 2.0, v52\n\t"
        "v_add_f32 v52, -1.0, v52\n\t"
        "v_mul_f32 v32, v52, v51\n\t"
        "ds_write_b32 v43, v32\n\t"
        "v_add_u32 v42, 0x800, v42\n\t"
        "v_add_u32 v43, 0x200, v43\n\t"
        "v_xor_b32 v40, 0x2000, v40\n\t"
        "v_xor_b32 v41, 0x2000, v41\n\t"
        "s_sub_u32 s22, s22, 1\n\t"
        "s_cmp_lg_u32 s22, 0\n\t"
        "s_cbranch_scc1 Lstep_%=\n\t"
        "s_waitcnt lgkmcnt(0)\n\t"
        :
        : "v"(f_lo), "v"(f_hi), "v"(i_lo), "v"(i_hi),
          "v"(c_lo), "v"(c_hi), "v"(o_lo), "v"(o_hi),
          "v"(pw), "v"(pr), "v"(ga), "v"(ha)
        : "memory", "vcc", "scc", "s20", "s21", "s22",
          "v32","v33","v34","v35","v36","v37","v38","v39",
          "v40","v41","v42","v43","v44","v45","v46","v47",
          "v48","v49","v50","v51","v52","v53","v54","v55",
          "v56","v57","v58","v59","v60","v61","v62","v63",
          "v64","v65","v66","v67","v68","v69","v70","v71",
          "v72","v73","v74","v75","v76","v77","v78","v79",
          "v80","v81","v82","v83","v84","v85","v86","v87",
          "v88","v89","v90","v91","v92","v93","v94","v95",
          "v96","v97","v98","v99","v100","v101","v102","v103",
          "v104","v105","v106","v107","v108","v109","v110","v111",
          "v112","v113","v114","v115","v116","v117","v118","v119",
          "v120","v121","v122","v123","v124","v125","v126","v127",
          "v128","v129","v130","v131","v132","v133","v134","v135",
          "v136","v137","v138","v139","v140","v141","v142","v143",
          "v144","v145","v146","v147","v148","v149","v150","v151",
          "v152","v153","v154","v155","v156","v157","v158","v159",
          "v160","v161","v162","v163","v164","v165","v166","v167",
          "v168","v169","v170","v171","v172","v173","v174","v175",
          "v176","v177","v178","v179","v180","v181","v182","v183",
          "v184","v185","v186","v187","v188","v189","v190","v191");

    __syncthreads();                          // hist read cross-wave below

    // Epilogue: out[b][t] = hist[t] . out_w + out_b, 16 threads per t.
    int tt = tid >> 4, j = tid & 15;
    const float4* hh = (const float4*)(&hist[tt][j * 8]);
    float4 a0q = hh[0], a1q = hh[1];
    const float* owp = out_w + j * 8;
    float pwv = a0q.x * owp[0] + a0q.y * owp[1] + a0q.z * owp[2] + a0q.w * owp[3]
              + a1q.x * owp[4] + a1q.y * owp[5] + a1q.z * owp[6] + a1q.w * owp[7];
#pragma unroll
    for (int off = 8; off > 0; off >>= 1) pwv += __shfl_down(pwv, off, 16);
    if (j == 0) out[b * Tt + tt] = pwv + out_b[0];
}

// ---------------------------------------------------------------------------
extern "C" void kernel_launch(void* const* d_in, const int* in_sizes, int n_in,
                              void* d_out, int out_size, void* d_ws, size_t ws_size,
                              hipStream_t stream) {
    const float* x   = (const float*)d_in[0];
    const float* w1  = (const float*)d_in[1];
    const float* b1  = (const float*)d_in[2];
    const float* w2  = (const float*)d_in[3];
    const float* b2  = (const float*)d_in[4];
    const float* Wf  = (const float*)d_in[5];
    const float* bf  = (const float*)d_in[6];
    const float* Wi  = (const float*)d_in[7];
    const float* bi  = (const float*)d_in[8];
    const float* Wc  = (const float*)d_in[9];
    const float* bc  = (const float*)d_in[10];
    const float* Wo  = (const float*)d_in[11];
    const float* bo  = (const float*)d_in[12];
    const float* ow  = (const float*)d_in[13];
    const float* ob  = (const float*)d_in[14];
    float* out = (float*)d_out;

    float* G = (float*)d_ws;                  // 256*512 = 131072 floats

    convfeat_kernel<<<Bb * Tt, 256, 0, stream>>>(x, w1, b1, w2, b2,
                                                 Wf, bf, Wi, bi, Wc, bc, Wo, bo, G);
    lstm_kernel<<<Bb, 512, 0, stream>>>(G, Wf, Wi, Wc, Wo, ow, ob, out);
}